// Round 1
// baseline (873.273 us; speedup 1.0000x reference)
//
#include <hip/hip_runtime.h>

#define N_NODES 50000
#define M_EDGES 800000

typedef __bf16 bf16x8 __attribute__((ext_vector_type(8)));
typedef __bf16 bf16x4 __attribute__((ext_vector_type(4)));
typedef float  f32x4  __attribute__((ext_vector_type(4)));

static __device__ __forceinline__ unsigned enc_ord(float f) {
    unsigned b = __float_as_uint(f);
    return (b & 0x80000000u) ? ~b : (b | 0x80000000u);
}
static __device__ __forceinline__ float dec_ord(unsigned u) {
    unsigned b = (u & 0x80000000u) ? (u ^ 0x80000000u) : ~u;
    return __uint_as_float(b);
}
// bf16 pair packed in a uint: lo = bits[15:0], hi = bits[31:16]
static __device__ __forceinline__ float bflo(unsigned u) { return __uint_as_float(u << 16); }
static __device__ __forceinline__ float bfhi(unsigned u) { return __uint_as_float(u & 0xffff0000u); }

__global__ void init_kernel(int* counts, int* cursor, unsigned* gmax) {
    int t = blockIdx.x * blockDim.x + threadIdx.x;
    if (t < N_NODES) { counts[t] = 0; cursor[t] = 0; }
    if (t == 0) *gmax = 0u;
}

__global__ void wsplit_kernel(const float* __restrict__ W,
                              __bf16* __restrict__ th, __bf16* __restrict__ tl) {
    int t = blockIdx.x * 256 + threadIdx.x;
    int n = t >> 8, k = t & 255;
    float v = W[(size_t)k * 256 + n];
    __bf16 h = (__bf16)v;
    th[t] = h;
    tl[t] = (__bf16)(v - (float)h);
}

// ---- split-bf16 MFMA GEMM. Output: fp32 C (with optional relu/residual) OR bf16 Cb.
__global__ __launch_bounds__(256) void gemm_mfma(
    const float* __restrict__ A,
    const __bf16* __restrict__ Bth, const __bf16* __restrict__ Btl,
    const float* __restrict__ bias, const float* __restrict__ residual,
    float* __restrict__ C, __bf16* __restrict__ Cb, int nrows, int do_relu) {
    __shared__ __attribute__((aligned(16))) __bf16 sAh[128 * 40];
    __shared__ __attribute__((aligned(16))) __bf16 sAl[128 * 40];
    __shared__ __attribute__((aligned(16))) __bf16 sBh[128 * 40];
    __shared__ __attribute__((aligned(16))) __bf16 sBl[128 * 40];

    int row0 = blockIdx.x * 128;
    int n0   = blockIdx.y * 128;
    int tid  = threadIdx.x;
    int lane = tid & 63, wave = tid >> 6;
    int wm = (wave >> 1) * 64, wn = (wave & 1) * 64;

    f32x4 acc[4][4];
    #pragma unroll
    for (int i = 0; i < 4; i++)
        #pragma unroll
        for (int j = 0; j < 4; j++) acc[i][j] = (f32x4)(0.f);

    int r  = tid >> 1;
    int hf = tid & 1;

    for (int kk = 0; kk < 256; kk += 32) {
        {
            const float* ap = A + (size_t)(row0 + r) * 256 + kk + hf * 16;
            bool valid = (row0 + r) < nrows;
            #pragma unroll
            for (int q = 0; q < 4; q++) {
                float4 v = valid ? *(const float4*)(ap + q * 4)
                                 : make_float4(0.f, 0.f, 0.f, 0.f);
                bf16x4 hh, ll;
                hh[0] = (__bf16)v.x; ll[0] = (__bf16)(v.x - (float)hh[0]);
                hh[1] = (__bf16)v.y; ll[1] = (__bf16)(v.y - (float)hh[1]);
                hh[2] = (__bf16)v.z; ll[2] = (__bf16)(v.z - (float)hh[2]);
                hh[3] = (__bf16)v.w; ll[3] = (__bf16)(v.w - (float)hh[3]);
                *(bf16x4*)&sAh[r * 40 + hf * 16 + q * 4] = hh;
                *(bf16x4*)&sAl[r * 40 + hf * 16 + q * 4] = ll;
            }
        }
        {
            size_t gb = (size_t)(n0 + r) * 256 + kk + hf * 16;
            uint4 vh0 = *(const uint4*)(Bth + gb);
            uint4 vh1 = *(const uint4*)(Bth + gb + 8);
            uint4 vl0 = *(const uint4*)(Btl + gb);
            uint4 vl1 = *(const uint4*)(Btl + gb + 8);
            *(uint4*)&sBh[r * 40 + hf * 16]     = vh0;
            *(uint4*)&sBh[r * 40 + hf * 16 + 8] = vh1;
            *(uint4*)&sBl[r * 40 + hf * 16]     = vl0;
            *(uint4*)&sBl[r * 40 + hf * 16 + 8] = vl1;
        }
        __syncthreads();

        int m_base = wm + (lane & 15);
        int n_base = wn + (lane & 15);
        int koff = (lane >> 4) * 8;
        bf16x8 ah[4], al[4], bh[4], bl[4];
        #pragma unroll
        for (int mt = 0; mt < 4; mt++) {
            ah[mt] = *(const bf16x8*)&sAh[(m_base + mt * 16) * 40 + koff];
            al[mt] = *(const bf16x8*)&sAl[(m_base + mt * 16) * 40 + koff];
        }
        #pragma unroll
        for (int nt = 0; nt < 4; nt++) {
            bh[nt] = *(const bf16x8*)&sBh[(n_base + nt * 16) * 40 + koff];
            bl[nt] = *(const bf16x8*)&sBl[(n_base + nt * 16) * 40 + koff];
        }
        #pragma unroll
        for (int mt = 0; mt < 4; mt++)
            #pragma unroll
            for (int nt = 0; nt < 4; nt++) {
                acc[mt][nt] = __builtin_amdgcn_mfma_f32_16x16x32_bf16(ah[mt], bh[nt], acc[mt][nt], 0, 0, 0);
                acc[mt][nt] = __builtin_amdgcn_mfma_f32_16x16x32_bf16(al[mt], bh[nt], acc[mt][nt], 0, 0, 0);
                acc[mt][nt] = __builtin_amdgcn_mfma_f32_16x16x32_bf16(ah[mt], bl[nt], acc[mt][nt], 0, 0, 0);
            }
        __syncthreads();
    }

    #pragma unroll
    for (int mt = 0; mt < 4; mt++) {
        #pragma unroll
        for (int nt = 0; nt < 4; nt++) {
            int col = n0 + wn + nt * 16 + (lane & 15);
            #pragma unroll
            for (int rr = 0; rr < 4; rr++) {
                int row = row0 + wm + mt * 16 + (lane >> 4) * 4 + rr;
                if (row < nrows) {
                    float v = acc[mt][nt][rr] + bias[col];
                    if (do_relu) v = fmaxf(v, 0.f);
                    if (Cb) {
                        Cb[(size_t)row * 256 + col] = (__bf16)v;
                    } else {
                        if (residual) v += residual[(size_t)row * 256 + col];
                        C[(size_t)row * 256 + col] = v;
                    }
                }
            }
        }
    }
}

// ---- CSR build ----
__global__ void hist_kernel(const int* __restrict__ recv, int* __restrict__ counts) {
    int t = blockIdx.x * 256 + threadIdx.x;
    if (t < M_EDGES) atomicAdd(&counts[recv[t]], 1);
}

__global__ void scan_kernel(const int* __restrict__ counts, int* __restrict__ offsets) {
    __shared__ int part[256];
    int t = threadIdx.x;
    const int per = (N_NODES + 255) / 256;
    int start = t * per;
    int end = min(start + per, N_NODES);
    int s = 0;
    for (int i = start; i < end; i++) s += counts[i];
    part[t] = s;
    __syncthreads();
    if (t == 0) {
        int acc = 0;
        for (int i = 0; i < 256; i++) { int v = part[i]; part[i] = acc; acc += v; }
    }
    __syncthreads();
    int acc = part[t];
    for (int i = start; i < end; i++) { offsets[i] = acc; acc += counts[i]; }
    if (end == N_NODES && start < N_NODES) offsets[N_NODES] = acc;
}

__global__ void fill_kernel(const int* __restrict__ recv, const int* __restrict__ send,
                            const int* __restrict__ offsets,
                            int* __restrict__ cursor, int* __restrict__ ssorted,
                            int* __restrict__ rsorted) {
    int t = blockIdx.x * 256 + threadIdx.x;
    if (t < M_EDGES) {
        int r = recv[t];
        int pos = offsets[r] + atomicAdd(&cursor[r], 1);
        ssorted[pos] = send[t];
        rsorted[pos] = r;
    }
}

// ---- edge logits. CONTIGUOUS per-wave pair chunks (rsorted is receiver-sorted, so
// a wave's consecutive iterations + both slots hit the SAME receiver's Q row ->
// L1-resident instead of 8 cross-XCD L2 fetches). Wave-iter = 2 adjacent pairs
// (slots A,B), 32 lanes x 16B per K row.
__global__ __launch_bounds__(256) void qk_csr_kernel(
    const int* __restrict__ ssorted, const int* __restrict__ rsorted,
    const float* __restrict__ Q, const unsigned short* __restrict__ Kb,
    float* __restrict__ qks, unsigned* __restrict__ gmax) {
    int wave_id = (blockIdx.x * 256 + threadIdx.x) >> 6;
    int lane = threadIdx.x & 63;
    int e_slot = lane >> 5;        // which edge of the pair
    int sl = lane & 31;            // 16B chunk within row
    const int nwaves = (gridDim.x * 256) >> 6;
    const int npairs = M_EDGES / 2;
    const int per = (npairs + nwaves - 1) / nwaves;   // pairs per wave (contiguous)
    int p0 = wave_id * per;
    int pend = min(p0 + per, npairs);
    float wmax = -INFINITY;
    for (int pp = p0; pp < pend; pp += 2) {
        int ppB = pp + 1;
        bool hasB = ppB < pend;
        int pA = pp * 2 + e_slot;
        int pB = (hasB ? ppB * 2 : pp * 2) + e_slot;
        // independent slot loads — index/receiver (broadcast within half-wave)
        int sA = ssorted[pA], rA = rsorted[pA];
        int sB = ssorted[pB], rB = rsorted[pB];
        uint4 kA = *(const uint4*)(Kb + (size_t)sA * 256 + sl * 8);
        uint4 kB = *(const uint4*)(Kb + (size_t)sB * 256 + sl * 8);
        float4 qaA = *(const float4*)(Q + (size_t)rA * 256 + sl * 8);
        float4 qbA = *(const float4*)(Q + (size_t)rA * 256 + sl * 8 + 4);
        float4 qaB = *(const float4*)(Q + (size_t)rB * 256 + sl * 8);
        float4 qbB = *(const float4*)(Q + (size_t)rB * 256 + sl * 8 + 4);
        float dA = qaA.x * bflo(kA.x) + qaA.y * bfhi(kA.x)
                 + qaA.z * bflo(kA.y) + qaA.w * bfhi(kA.y)
                 + qbA.x * bflo(kA.z) + qbA.y * bfhi(kA.z)
                 + qbA.z * bflo(kA.w) + qbA.w * bfhi(kA.w);
        float dB = qaB.x * bflo(kB.x) + qaB.y * bfhi(kB.x)
                 + qaB.z * bflo(kB.y) + qaB.w * bfhi(kB.y)
                 + qbB.x * bflo(kB.z) + qbB.y * bfhi(kB.z)
                 + qbB.z * bflo(kB.w) + qbB.w * bfhi(kB.w);
        dA += __shfl_xor(dA, 1); dA += __shfl_xor(dA, 2);
        dB += __shfl_xor(dB, 1); dB += __shfl_xor(dB, 2);
        wmax = fmaxf(wmax, fmaxf(dA, dB));
        if ((sl & 3) == 0) {
            qks[(size_t)pA * 8 + (sl >> 2)] = dA;
            if (hasB) qks[(size_t)pB * 8 + (sl >> 2)] = dB;
        }
    }
    // wave max reduce + one atomic per wave
    wmax = fmaxf(wmax, __shfl_xor(wmax, 1));
    wmax = fmaxf(wmax, __shfl_xor(wmax, 2));
    wmax = fmaxf(wmax, __shfl_xor(wmax, 4));
    wmax = fmaxf(wmax, __shfl_xor(wmax, 8));
    wmax = fmaxf(wmax, __shfl_xor(wmax, 16));
    wmax = fmaxf(wmax, __shfl_xor(wmax, 32));
    if (lane == 0 && wmax > -INFINITY) atomicMax(gmax, enc_ord(wmax));
}

// ---- node aggregation: one wave per node (64 lanes x 4 cols = 256), CONTIGUOUS
// per-wave node chunks (sequential offsets/ssorted/qks walk per wave).
// Every lane sees every edge -> per-head softmax sum needs NO reduction; no LDS/sync.
__global__ __launch_bounds__(256) void node_agg_kernel(
    const int* __restrict__ offsets, const int* __restrict__ ssorted,
    const float* __restrict__ qks, const unsigned short* __restrict__ Vb,
    const unsigned* __restrict__ gmax, float* __restrict__ msg) {
    int wave_id = (blockIdx.x * 256 + threadIdx.x) >> 6;
    int lane = threadIdx.x & 63;   // columns lane*4 .. lane*4+3
    int h = lane >> 3;             // head of these columns
    const int nwaves = (gridDim.x * 256) >> 6;
    const int per = (N_NODES + nwaves - 1) / nwaves;
    int n0 = wave_id * per;
    int nend = min(n0 + per, N_NODES);
    float scale = 3.0f / dec_ord(*gmax);
    for (int n = n0; n < nend; n++) {
        int off = offsets[n];
        int deg = offsets[n + 1] - off;
        float sum = 0.f, a0 = 0.f, a1 = 0.f, a2 = 0.f, a3 = 0.f;
        for (int b = 0; b < deg; b += 64) {
            int bn = min(64, deg - b);
            int idxb = ssorted[off + b + min(lane, bn - 1)];  // coalesced index batch
            #define VROW(i) (*(const uint2*)(Vb + \
                (size_t)__shfl(idxb, min((i), bn - 1)) * 256 + lane * 4))
            #define QKL(i) qks[(size_t)(off + b + min((i), bn - 1)) * 8 + h]
            uint2 v0 = VROW(0);
            uint2 v1 = VROW(1);
            float q0 = QKL(0);
            float q1 = QKL(1);
            for (int i = 0; i < bn; i++) {
                uint2 vc = v0; v0 = v1; v1 = VROW(i + 2);
                float qc = q0; q0 = q1; q1 = QKL(i + 2);
                float a = __expf(qc * scale);
                sum += a;
                a0 += a * bflo(vc.x); a1 += a * bfhi(vc.x);
                a2 += a * bflo(vc.y); a3 += a * bfhi(vc.y);
            }
            #undef VROW
            #undef QKL
        }
        float inv = (deg > 0) ? 1.0f / (sum * 5.65685424949238f) : 0.f;  // sqrt(32)
        *(float4*)(msg + (size_t)n * 256 + lane * 4) =
            make_float4(fmaxf(a0 * inv, 0.f), fmaxf(a1 * inv, 0.f),
                        fmaxf(a2 * inv, 0.f), fmaxf(a3 * inv, 0.f));
    }
}

extern "C" void kernel_launch(void* const* d_in, const int* in_sizes, int n_in,
                              void* d_out, int out_size, void* d_ws, size_t ws_size,
                              hipStream_t stream) {
    const float* x    = (const float*)d_in[0];
    const int*   edge = (const int*)d_in[1];
    const int*   recv = edge;
    const int*   send = edge + M_EDGES;
    const float* Wk   = (const float*)d_in[2];
    const float* bk   = (const float*)d_in[3];
    const float* Wq   = (const float*)d_in[4];
    const float* bq   = (const float*)d_in[5];
    const float* Wv   = (const float*)d_in[6];
    const float* bv   = (const float*)d_in[7];
    const float* Wagg = (const float*)d_in[8];
    const float* bagg = (const float*)d_in[9];
    const float* Wff  = (const float*)d_in[10];
    const float* bff  = (const float*)d_in[11];
    float* out = (float*)d_out;

    float*  Qbuf  = (float*)d_ws;
    float*  msg   = Qbuf + (size_t)N_NODES * 256;
    float*  qks   = msg + (size_t)N_NODES * 256;
    __bf16* Kbf   = (__bf16*)(qks + (size_t)M_EDGES * 8);
    __bf16* Vbf   = Kbf + (size_t)N_NODES * 256;
    int* counts   = (int*)(Vbf + (size_t)N_NODES * 256);
    int* cursor   = counts + N_NODES;
    int* offsets  = cursor + N_NODES;
    int* ssorted  = offsets + N_NODES + 1;
    unsigned* gmax = (unsigned*)(ssorted + M_EDGES);
    __bf16* wt    = (__bf16*)(gmax + 1);
    __bf16* WkH = wt;              __bf16* WkL = wt + 65536;
    __bf16* WqH = wt + 2 * 65536;  __bf16* WqL = wt + 3 * 65536;
    __bf16* WvH = wt + 4 * 65536;  __bf16* WvL = wt + 5 * 65536;
    __bf16* WaH = wt + 6 * 65536;  __bf16* WaL = wt + 7 * 65536;
    __bf16* WfH = wt + 8 * 65536;  __bf16* WfL = wt + 9 * 65536;
    // rsorted overlays msg: live only during fill->qk, before node_agg writes msg
    int* rsorted  = (int*)msg;
    float* hidden = Qbuf;  // reuse: Q dead after qk_csr_kernel

    dim3 blk(256);
    dim3 gemm_grid((N_NODES + 127) / 128, 2);
    dim3 edge_grid((M_EDGES + 255) / 256);

    hipLaunchKernelGGL(init_kernel, dim3((N_NODES + 255) / 256), blk, 0, stream,
                       counts, cursor, gmax);
    hipLaunchKernelGGL(wsplit_kernel, dim3(256), blk, 0, stream, Wk,   WkH, WkL);
    hipLaunchKernelGGL(wsplit_kernel, dim3(256), blk, 0, stream, Wq,   WqH, WqL);
    hipLaunchKernelGGL(wsplit_kernel, dim3(256), blk, 0, stream, Wv,   WvH, WvL);
    hipLaunchKernelGGL(wsplit_kernel, dim3(256), blk, 0, stream, Wagg, WaH, WaL);
    hipLaunchKernelGGL(wsplit_kernel, dim3(256), blk, 0, stream, Wff,  WfH, WfL);
    // projections (MFMA); K,V emitted as bf16, Q fp32
    hipLaunchKernelGGL(gemm_mfma, gemm_grid, blk, 0, stream, x, WkH, WkL, bk, nullptr,
                       (float*)nullptr, Kbf, N_NODES, 0);
    hipLaunchKernelGGL(gemm_mfma, gemm_grid, blk, 0, stream, x, WqH, WqL, bq, nullptr,
                       Qbuf, (__bf16*)nullptr, N_NODES, 0);
    hipLaunchKernelGGL(gemm_mfma, gemm_grid, blk, 0, stream, x, WvH, WvL, bv, nullptr,
                       (float*)nullptr, Vbf, N_NODES, 0);
    // CSR build
    hipLaunchKernelGGL(hist_kernel, edge_grid, blk, 0, stream, recv, counts);
    hipLaunchKernelGGL(scan_kernel, dim3(1), blk, 0, stream, counts, offsets);
    hipLaunchKernelGGL(fill_kernel, edge_grid, blk, 0, stream, recv, send, offsets,
                       cursor, ssorted, rsorted);
    // edge logits + global max (persistent, contiguous chunks, full residency)
    hipLaunchKernelGGL(qk_csr_kernel, dim3(2048), blk, 0, stream,
                       ssorted, rsorted, Qbuf, (const unsigned short*)Kbf, qks, gmax);
    // segment softmax + aggregate (persistent, wave-per-node, contiguous chunks)
    hipLaunchKernelGGL(node_agg_kernel, dim3(2048), blk, 0, stream,
                       offsets, ssorted, qks, (const unsigned short*)Vbf, gmax, msg);
    // output MLP (MFMA)
    hipLaunchKernelGGL(gemm_mfma, gemm_grid, blk, 0, stream, msg, WaH, WaL, bagg, nullptr,
                       hidden, (__bf16*)nullptr, N_NODES, 1);
    hipLaunchKernelGGL(gemm_mfma, gemm_grid, blk, 0, stream, hidden, WfH, WfL, bff, x,
                       out, (__bf16*)nullptr, N_NODES, 1);
}

// Round 2
// 845.434 us; speedup vs baseline: 1.0329x; 1.0329x over previous
//
#include <hip/hip_runtime.h>

#define N_NODES 50000
#define M_EDGES 800000

typedef __bf16 bf16x8 __attribute__((ext_vector_type(8)));
typedef __bf16 bf16x4 __attribute__((ext_vector_type(4)));
typedef float  f32x4  __attribute__((ext_vector_type(4)));

static __device__ __forceinline__ unsigned enc_ord(float f) {
    unsigned b = __float_as_uint(f);
    return (b & 0x80000000u) ? ~b : (b | 0x80000000u);
}
static __device__ __forceinline__ float dec_ord(unsigned u) {
    unsigned b = (u & 0x80000000u) ? (u ^ 0x80000000u) : ~u;
    return __uint_as_float(b);
}
// bf16 pair packed in a uint: lo = bits[15:0], hi = bits[31:16]
static __device__ __forceinline__ float bflo(unsigned u) { return __uint_as_float(u << 16); }
static __device__ __forceinline__ float bfhi(unsigned u) { return __uint_as_float(u & 0xffff0000u); }

__global__ void init_kernel(int* counts, int* cursor, unsigned* gmax) {
    int t = blockIdx.x * blockDim.x + threadIdx.x;
    if (t < N_NODES) { counts[t] = 0; cursor[t] = 0; }
    if (t == 0) *gmax = 0u;
}

__global__ void wsplit_kernel(const float* __restrict__ W,
                              __bf16* __restrict__ th, __bf16* __restrict__ tl) {
    int t = blockIdx.x * 256 + threadIdx.x;
    int n = t >> 8, k = t & 255;
    float v = W[(size_t)k * 256 + n];
    __bf16 h = (__bf16)v;
    th[t] = h;
    tl[t] = (__bf16)(v - (float)h);
}

// ---- split-bf16 MFMA GEMM. Output: fp32 C (with optional relu/residual) OR bf16 Cb.
__global__ __launch_bounds__(256) void gemm_mfma(
    const float* __restrict__ A,
    const __bf16* __restrict__ Bth, const __bf16* __restrict__ Btl,
    const float* __restrict__ bias, const float* __restrict__ residual,
    float* __restrict__ C, __bf16* __restrict__ Cb, int nrows, int do_relu) {
    __shared__ __attribute__((aligned(16))) __bf16 sAh[128 * 40];
    __shared__ __attribute__((aligned(16))) __bf16 sAl[128 * 40];
    __shared__ __attribute__((aligned(16))) __bf16 sBh[128 * 40];
    __shared__ __attribute__((aligned(16))) __bf16 sBl[128 * 40];

    int row0 = blockIdx.x * 128;
    int n0   = blockIdx.y * 128;
    int tid  = threadIdx.x;
    int lane = tid & 63, wave = tid >> 6;
    int wm = (wave >> 1) * 64, wn = (wave & 1) * 64;

    f32x4 acc[4][4];
    #pragma unroll
    for (int i = 0; i < 4; i++)
        #pragma unroll
        for (int j = 0; j < 4; j++) acc[i][j] = (f32x4)(0.f);

    int r  = tid >> 1;
    int hf = tid & 1;

    for (int kk = 0; kk < 256; kk += 32) {
        {
            const float* ap = A + (size_t)(row0 + r) * 256 + kk + hf * 16;
            bool valid = (row0 + r) < nrows;
            #pragma unroll
            for (int q = 0; q < 4; q++) {
                float4 v = valid ? *(const float4*)(ap + q * 4)
                                 : make_float4(0.f, 0.f, 0.f, 0.f);
                bf16x4 hh, ll;
                hh[0] = (__bf16)v.x; ll[0] = (__bf16)(v.x - (float)hh[0]);
                hh[1] = (__bf16)v.y; ll[1] = (__bf16)(v.y - (float)hh[1]);
                hh[2] = (__bf16)v.z; ll[2] = (__bf16)(v.z - (float)hh[2]);
                hh[3] = (__bf16)v.w; ll[3] = (__bf16)(v.w - (float)hh[3]);
                *(bf16x4*)&sAh[r * 40 + hf * 16 + q * 4] = hh;
                *(bf16x4*)&sAl[r * 40 + hf * 16 + q * 4] = ll;
            }
        }
        {
            size_t gb = (size_t)(n0 + r) * 256 + kk + hf * 16;
            uint4 vh0 = *(const uint4*)(Bth + gb);
            uint4 vh1 = *(const uint4*)(Bth + gb + 8);
            uint4 vl0 = *(const uint4*)(Btl + gb);
            uint4 vl1 = *(const uint4*)(Btl + gb + 8);
            *(uint4*)&sBh[r * 40 + hf * 16]     = vh0;
            *(uint4*)&sBh[r * 40 + hf * 16 + 8] = vh1;
            *(uint4*)&sBl[r * 40 + hf * 16]     = vl0;
            *(uint4*)&sBl[r * 40 + hf * 16 + 8] = vl1;
        }
        __syncthreads();

        int m_base = wm + (lane & 15);
        int n_base = wn + (lane & 15);
        int koff = (lane >> 4) * 8;
        bf16x8 ah[4], al[4], bh[4], bl[4];
        #pragma unroll
        for (int mt = 0; mt < 4; mt++) {
            ah[mt] = *(const bf16x8*)&sAh[(m_base + mt * 16) * 40 + koff];
            al[mt] = *(const bf16x8*)&sAl[(m_base + mt * 16) * 40 + koff];
        }
        #pragma unroll
        for (int nt = 0; nt < 4; nt++) {
            bh[nt] = *(const bf16x8*)&sBh[(n_base + nt * 16) * 40 + koff];
            bl[nt] = *(const bf16x8*)&sBl[(n_base + nt * 16) * 40 + koff];
        }
        #pragma unroll
        for (int mt = 0; mt < 4; mt++)
            #pragma unroll
            for (int nt = 0; nt < 4; nt++) {
                acc[mt][nt] = __builtin_amdgcn_mfma_f32_16x16x32_bf16(ah[mt], bh[nt], acc[mt][nt], 0, 0, 0);
                acc[mt][nt] = __builtin_amdgcn_mfma_f32_16x16x32_bf16(al[mt], bh[nt], acc[mt][nt], 0, 0, 0);
                acc[mt][nt] = __builtin_amdgcn_mfma_f32_16x16x32_bf16(ah[mt], bl[nt], acc[mt][nt], 0, 0, 0);
            }
        __syncthreads();
    }

    #pragma unroll
    for (int mt = 0; mt < 4; mt++) {
        #pragma unroll
        for (int nt = 0; nt < 4; nt++) {
            int col = n0 + wn + nt * 16 + (lane & 15);
            #pragma unroll
            for (int rr = 0; rr < 4; rr++) {
                int row = row0 + wm + mt * 16 + (lane >> 4) * 4 + rr;
                if (row < nrows) {
                    float v = acc[mt][nt][rr] + bias[col];
                    if (do_relu) v = fmaxf(v, 0.f);
                    if (Cb) {
                        Cb[(size_t)row * 256 + col] = (__bf16)v;
                    } else {
                        if (residual) v += residual[(size_t)row * 256 + col];
                        C[(size_t)row * 256 + col] = v;
                    }
                }
            }
        }
    }
}

// ---- CSR build ----
__global__ void hist_kernel(const int* __restrict__ recv, int* __restrict__ counts) {
    int t = blockIdx.x * 256 + threadIdx.x;
    if (t < M_EDGES) atomicAdd(&counts[recv[t]], 1);
}

__global__ void scan_kernel(const int* __restrict__ counts, int* __restrict__ offsets) {
    __shared__ int part[256];
    int t = threadIdx.x;
    const int per = (N_NODES + 255) / 256;
    int start = t * per;
    int end = min(start + per, N_NODES);
    int s = 0;
    for (int i = start; i < end; i++) s += counts[i];
    part[t] = s;
    __syncthreads();
    if (t == 0) {
        int acc = 0;
        for (int i = 0; i < 256; i++) { int v = part[i]; part[i] = acc; acc += v; }
    }
    __syncthreads();
    int acc = part[t];
    for (int i = start; i < end; i++) { offsets[i] = acc; acc += counts[i]; }
    if (end == N_NODES && start < N_NODES) offsets[N_NODES] = acc;
}

__global__ void fill_kernel(const int* __restrict__ recv, const int* __restrict__ send,
                            const int* __restrict__ offsets,
                            int* __restrict__ cursor, int* __restrict__ ssorted,
                            int* __restrict__ rsorted) {
    int t = blockIdx.x * 256 + threadIdx.x;
    if (t < M_EDGES) {
        int r = recv[t];
        int pos = offsets[r] + atomicAdd(&cursor[r], 1);
        ssorted[pos] = send[t];
        rsorted[pos] = r;
    }
}

// ---- edge logits. GRID-STRIDE sliding window (all waves stay inside one
// ~16K-edge window -> instantaneous Q working set ~1MB, L2-shared) with
// 4 independent slots per wave-iteration for memory-level parallelism.
// Slot = 1 pair = 2 edges (e_slot picks edge, 32 lanes x 16B per K row).
__global__ __launch_bounds__(256) void qk_csr_kernel(
    const int* __restrict__ ssorted, const int* __restrict__ rsorted,
    const float* __restrict__ Q, const unsigned short* __restrict__ Kb,
    float* __restrict__ qks, unsigned* __restrict__ gmax) {
    int wave_id = (blockIdx.x * 256 + threadIdx.x) >> 6;
    int lane = threadIdx.x & 63;
    int e_slot = lane >> 5;        // which edge of the pair
    int sl = lane & 31;            // 16B chunk within row
    const int nwaves = (gridDim.x * 256) >> 6;
    const int npairs = M_EDGES / 2;
    float wmax = -INFINITY;
    for (int pp = wave_id; pp < npairs; pp += 4 * nwaves) {
        int ep[4]; bool valid[4];
        #pragma unroll
        for (int u = 0; u < 4; u++) {
            int p = pp + u * nwaves;
            valid[u] = p < npairs;
            ep[u] = (valid[u] ? p : pp) * 2 + e_slot;
        }
        // batch all index loads, then all row gathers -> 4 independent chains
        int si[4], ri[4];
        #pragma unroll
        for (int u = 0; u < 4; u++) { si[u] = ssorted[ep[u]]; ri[u] = rsorted[ep[u]]; }
        uint4 kv[4]; float4 qa[4], qb[4];
        #pragma unroll
        for (int u = 0; u < 4; u++) {
            kv[u] = *(const uint4*)(Kb + (size_t)si[u] * 256 + sl * 8);
            qa[u] = *(const float4*)(Q + (size_t)ri[u] * 256 + sl * 8);
            qb[u] = *(const float4*)(Q + (size_t)ri[u] * 256 + sl * 8 + 4);
        }
        #pragma unroll
        for (int u = 0; u < 4; u++) {
            float d = qa[u].x * bflo(kv[u].x) + qa[u].y * bfhi(kv[u].x)
                    + qa[u].z * bflo(kv[u].y) + qa[u].w * bfhi(kv[u].y)
                    + qb[u].x * bflo(kv[u].z) + qb[u].y * bfhi(kv[u].z)
                    + qb[u].z * bflo(kv[u].w) + qb[u].w * bfhi(kv[u].w);
            d += __shfl_xor(d, 1);
            d += __shfl_xor(d, 2);
            wmax = fmaxf(wmax, d);
            if ((sl & 3) == 0 && valid[u])
                qks[(size_t)ep[u] * 8 + (sl >> 2)] = d;
        }
    }
    // wave max reduce + one atomic per wave
    wmax = fmaxf(wmax, __shfl_xor(wmax, 1));
    wmax = fmaxf(wmax, __shfl_xor(wmax, 2));
    wmax = fmaxf(wmax, __shfl_xor(wmax, 4));
    wmax = fmaxf(wmax, __shfl_xor(wmax, 8));
    wmax = fmaxf(wmax, __shfl_xor(wmax, 16));
    wmax = fmaxf(wmax, __shfl_xor(wmax, 32));
    if (lane == 0 && wmax > -INFINITY) atomicMax(gmax, enc_ord(wmax));
}

// ---- node aggregation: one wave per node (64 lanes x 4 cols = 256), CONTIGUOUS
// per-wave node chunks (sequential offsets/ssorted/qks walk per wave).
// Every lane sees every edge -> per-head softmax sum needs NO reduction; no LDS/sync.
__global__ __launch_bounds__(256) void node_agg_kernel(
    const int* __restrict__ offsets, const int* __restrict__ ssorted,
    const float* __restrict__ qks, const unsigned short* __restrict__ Vb,
    const unsigned* __restrict__ gmax, float* __restrict__ msg) {
    int wave_id = (blockIdx.x * 256 + threadIdx.x) >> 6;
    int lane = threadIdx.x & 63;   // columns lane*4 .. lane*4+3
    int h = lane >> 3;             // head of these columns
    const int nwaves = (gridDim.x * 256) >> 6;
    const int per = (N_NODES + nwaves - 1) / nwaves;
    int n0 = wave_id * per;
    int nend = min(n0 + per, N_NODES);
    float scale = 3.0f / dec_ord(*gmax);
    for (int n = n0; n < nend; n++) {
        int off = offsets[n];
        int deg = offsets[n + 1] - off;
        float sum = 0.f, a0 = 0.f, a1 = 0.f, a2 = 0.f, a3 = 0.f;
        for (int b = 0; b < deg; b += 64) {
            int bn = min(64, deg - b);
            int idxb = ssorted[off + b + min(lane, bn - 1)];  // coalesced index batch
            #define VROW(i) (*(const uint2*)(Vb + \
                (size_t)__shfl(idxb, min((i), bn - 1)) * 256 + lane * 4))
            #define QKL(i) qks[(size_t)(off + b + min((i), bn - 1)) * 8 + h]
            uint2 v0 = VROW(0);
            uint2 v1 = VROW(1);
            float q0 = QKL(0);
            float q1 = QKL(1);
            for (int i = 0; i < bn; i++) {
                uint2 vc = v0; v0 = v1; v1 = VROW(i + 2);
                float qc = q0; q0 = q1; q1 = QKL(i + 2);
                float a = __expf(qc * scale);
                sum += a;
                a0 += a * bflo(vc.x); a1 += a * bfhi(vc.x);
                a2 += a * bflo(vc.y); a3 += a * bfhi(vc.y);
            }
            #undef VROW
            #undef QKL
        }
        float inv = (deg > 0) ? 1.0f / (sum * 5.65685424949238f) : 0.f;  // sqrt(32)
        *(float4*)(msg + (size_t)n * 256 + lane * 4) =
            make_float4(fmaxf(a0 * inv, 0.f), fmaxf(a1 * inv, 0.f),
                        fmaxf(a2 * inv, 0.f), fmaxf(a3 * inv, 0.f));
    }
}

extern "C" void kernel_launch(void* const* d_in, const int* in_sizes, int n_in,
                              void* d_out, int out_size, void* d_ws, size_t ws_size,
                              hipStream_t stream) {
    const float* x    = (const float*)d_in[0];
    const int*   edge = (const int*)d_in[1];
    const int*   recv = edge;
    const int*   send = edge + M_EDGES;
    const float* Wk   = (const float*)d_in[2];
    const float* bk   = (const float*)d_in[3];
    const float* Wq   = (const float*)d_in[4];
    const float* bq   = (const float*)d_in[5];
    const float* Wv   = (const float*)d_in[6];
    const float* bv   = (const float*)d_in[7];
    const float* Wagg = (const float*)d_in[8];
    const float* bagg = (const float*)d_in[9];
    const float* Wff  = (const float*)d_in[10];
    const float* bff  = (const float*)d_in[11];
    float* out = (float*)d_out;

    float*  Qbuf  = (float*)d_ws;
    float*  msg   = Qbuf + (size_t)N_NODES * 256;
    float*  qks   = msg + (size_t)N_NODES * 256;
    __bf16* Kbf   = (__bf16*)(qks + (size_t)M_EDGES * 8);
    __bf16* Vbf   = Kbf + (size_t)N_NODES * 256;
    int* counts   = (int*)(Vbf + (size_t)N_NODES * 256);
    int* cursor   = counts + N_NODES;
    int* offsets  = cursor + N_NODES;
    int* ssorted  = offsets + N_NODES + 1;
    unsigned* gmax = (unsigned*)(ssorted + M_EDGES);
    __bf16* wt    = (__bf16*)(gmax + 1);
    __bf16* WkH = wt;              __bf16* WkL = wt + 65536;
    __bf16* WqH = wt + 2 * 65536;  __bf16* WqL = wt + 3 * 65536;
    __bf16* WvH = wt + 4 * 65536;  __bf16* WvL = wt + 5 * 65536;
    __bf16* WaH = wt + 6 * 65536;  __bf16* WaL = wt + 7 * 65536;
    __bf16* WfH = wt + 8 * 65536;  __bf16* WfL = wt + 9 * 65536;
    // rsorted overlays msg: live only during fill->qk, before node_agg writes msg
    int* rsorted  = (int*)msg;
    float* hidden = Qbuf;  // reuse: Q dead after qk_csr_kernel

    dim3 blk(256);
    dim3 gemm_grid((N_NODES + 127) / 128, 2);
    dim3 edge_grid((M_EDGES + 255) / 256);

    hipLaunchKernelGGL(init_kernel, dim3((N_NODES + 255) / 256), blk, 0, stream,
                       counts, cursor, gmax);
    hipLaunchKernelGGL(wsplit_kernel, dim3(256), blk, 0, stream, Wk,   WkH, WkL);
    hipLaunchKernelGGL(wsplit_kernel, dim3(256), blk, 0, stream, Wq,   WqH, WqL);
    hipLaunchKernelGGL(wsplit_kernel, dim3(256), blk, 0, stream, Wv,   WvH, WvL);
    hipLaunchKernelGGL(wsplit_kernel, dim3(256), blk, 0, stream, Wagg, WaH, WaL);
    hipLaunchKernelGGL(wsplit_kernel, dim3(256), blk, 0, stream, Wff,  WfH, WfL);
    // projections (MFMA); K,V emitted as bf16, Q fp32
    hipLaunchKernelGGL(gemm_mfma, gemm_grid, blk, 0, stream, x, WkH, WkL, bk, nullptr,
                       (float*)nullptr, Kbf, N_NODES, 0);
    hipLaunchKernelGGL(gemm_mfma, gemm_grid, blk, 0, stream, x, WqH, WqL, bq, nullptr,
                       Qbuf, (__bf16*)nullptr, N_NODES, 0);
    hipLaunchKernelGGL(gemm_mfma, gemm_grid, blk, 0, stream, x, WvH, WvL, bv, nullptr,
                       (float*)nullptr, Vbf, N_NODES, 0);
    // CSR build
    hipLaunchKernelGGL(hist_kernel, edge_grid, blk, 0, stream, recv, counts);
    hipLaunchKernelGGL(scan_kernel, dim3(1), blk, 0, stream, counts, offsets);
    hipLaunchKernelGGL(fill_kernel, edge_grid, blk, 0, stream, recv, send, offsets,
                       cursor, ssorted, rsorted);
    // edge logits + global max (persistent, sliding-window grid-stride, 4-slot ILP)
    hipLaunchKernelGGL(qk_csr_kernel, dim3(1024), blk, 0, stream,
                       ssorted, rsorted, Qbuf, (const unsigned short*)Kbf, qks, gmax);
    // segment softmax + aggregate (persistent, wave-per-node, contiguous chunks)
    hipLaunchKernelGGL(node_agg_kernel, dim3(2048), blk, 0, stream,
                       offsets, ssorted, qks, (const unsigned short*)Vbf, gmax, msg);
    // output MLP (MFMA)
    hipLaunchKernelGGL(gemm_mfma, gemm_grid, blk, 0, stream, msg, WaH, WaL, bagg, nullptr,
                       hidden, (__bf16*)nullptr, N_NODES, 1);
    hipLaunchKernelGGL(gemm_mfma, gemm_grid, blk, 0, stream, hidden, WfH, WfL, bff, x,
                       out, (__bf16*)nullptr, N_NODES, 1);
}